// Round 1
// baseline (50.324 us; speedup 1.0000x reference)
//
#include <hip/hip_runtime.h>

// EdgeCrossingLoss: F faces, K neighbors each. Output = sum_f prob_f * crossings_f
// where crossings counts (i,k,j) combos with t,u in [0,1],
//   cp = e_i x ne_kj ; denom = cp.e_i ; t = (cp.ne_kj)/denom ; u = (cp.e_j)/denom.
// denom and t-numerator are analytically 0 => pure fp32 rounding residues.
// => must match numpy's op order exactly: no FMA (contract off), dot = ((x+y)+z).
// Division replaced by sign-aware compares (identical except 1-ulp ties).

__device__ __forceinline__ int ec_count9(const float e[3][3], const float n[3][3]) {
#pragma clang fp contract(off)
    int cnt = 0;
#pragma unroll
    for (int i = 0; i < 3; ++i) {
#pragma unroll
        for (int j = 0; j < 3; ++j) {
            float c0 = e[i][1] * n[j][2] - e[i][2] * n[j][1];
            float c1 = e[i][2] * n[j][0] - e[i][0] * n[j][2];
            float c2 = e[i][0] * n[j][1] - e[i][1] * n[j][0];
            float d  = (c0 * e[i][0] + c1 * e[i][1]) + c2 * e[i][2];
            float tn = (c0 * n[j][0] + c1 * n[j][1]) + c2 * n[j][2];
            float un = (c0 * e[j][0] + c1 * e[j][1]) + c2 * e[j][2];
            // t = tn/d, u = un/d ; mask = t>=0 & t<=1 & u>=0 & u<=1
            // d>0: tn in [0,d] and un in [0,d]; d<0: tn in [d,0] and un in [d,0]; d==0 -> inf/nan -> false
            bool pos = (tn >= 0.f) & (tn <= d) & (un >= 0.f) & (un <= d);
            bool neg = (tn <= 0.f) & (tn >= d) & (un <= 0.f) & (un >= d);
            bool hit = (d > 0.f) ? pos : ((d < 0.f) ? neg : false);
            cnt += hit ? 1 : 0;
        }
    }
    return cnt;
}

__global__ __launch_bounds__(256) void ec_edges_kernel(
    const float* __restrict__ vertices, const int* __restrict__ faces,
    float4* __restrict__ edges, int F) {
#pragma clang fp contract(off)
    int f = blockIdx.x * blockDim.x + threadIdx.x;
    if (f >= F) return;
    int i0 = faces[3 * f + 0], i1 = faces[3 * f + 1], i2 = faces[3 * f + 2];
    float ax = vertices[3 * i0 + 0], ay = vertices[3 * i0 + 1], az = vertices[3 * i0 + 2];
    float bx = vertices[3 * i1 + 0], by = vertices[3 * i1 + 1], bz = vertices[3 * i1 + 2];
    float cx = vertices[3 * i2 + 0], cy = vertices[3 * i2 + 1], cz = vertices[3 * i2 + 2];
    edges[3 * f + 0] = make_float4(bx - ax, by - ay, bz - az, 0.f);
    edges[3 * f + 1] = make_float4(cx - bx, cy - by, cz - bz, 0.f);
    edges[3 * f + 2] = make_float4(ax - cx, ay - cy, az - cz, 0.f);
}

__device__ __forceinline__ float ec_block_reduce(float acc) {
    for (int off = 32; off > 0; off >>= 1) acc += __shfl_down(acc, off);
    __shared__ float ws[4];
    int lane = threadIdx.x & 63, wv = threadIdx.x >> 6;
    if (lane == 0) ws[wv] = acc;
    __syncthreads();
    float t = 0.f;
    if (threadIdx.x == 0) t = (ws[0] + ws[1]) + (ws[2] + ws[3]);
    return t;
}

__global__ __launch_bounds__(256) void ec_cross_ws_kernel(
    const float4* __restrict__ edges, const float* __restrict__ probs,
    const int* __restrict__ nbrs, float* __restrict__ out, int F, int K) {
#pragma clang fp contract(off)
    int P = F * K;
    int stride = gridDim.x * blockDim.x;
    float acc = 0.f;
    for (int p = blockIdx.x * blockDim.x + threadIdx.x; p < P; p += stride) {
        int f;
        if (K == 32) { f = p >> 5; } else { f = p / K; }
        int nb = nbrs[p];
        float4 E0 = edges[3 * f + 0], E1 = edges[3 * f + 1], E2 = edges[3 * f + 2];
        float4 N0 = edges[3 * nb + 0], N1 = edges[3 * nb + 1], N2 = edges[3 * nb + 2];
        float e[3][3] = {{E0.x, E0.y, E0.z}, {E1.x, E1.y, E1.z}, {E2.x, E2.y, E2.z}};
        float n[3][3] = {{N0.x, N0.y, N0.z}, {N1.x, N1.y, N1.z}, {N2.x, N2.y, N2.z}};
        int cnt = ec_count9(e, n);
        acc += probs[f] * (float)cnt;
    }
    float t = ec_block_reduce(acc);
    if (threadIdx.x == 0) atomicAdd(out, t);
}

__device__ __forceinline__ void ec_load_edges_direct(
    const float* __restrict__ v, const int* __restrict__ faces, int f, float e[3][3]) {
#pragma clang fp contract(off)
    int i0 = faces[3 * f + 0], i1 = faces[3 * f + 1], i2 = faces[3 * f + 2];
#pragma unroll
    for (int c = 0; c < 3; ++c) {
        float a = v[3 * i0 + c], b = v[3 * i1 + c], cc = v[3 * i2 + c];
        e[0][c] = b - a;
        e[1][c] = cc - b;
        e[2][c] = a - cc;
    }
}

__global__ __launch_bounds__(256) void ec_cross_nows_kernel(
    const float* __restrict__ vertices, const int* __restrict__ faces,
    const float* __restrict__ probs, const int* __restrict__ nbrs,
    float* __restrict__ out, int F, int K) {
#pragma clang fp contract(off)
    int P = F * K;
    int stride = gridDim.x * blockDim.x;
    float acc = 0.f;
    for (int p = blockIdx.x * blockDim.x + threadIdx.x; p < P; p += stride) {
        int f;
        if (K == 32) { f = p >> 5; } else { f = p / K; }
        int nb = nbrs[p];
        float e[3][3], n[3][3];
        ec_load_edges_direct(vertices, faces, f, e);
        ec_load_edges_direct(vertices, faces, nb, n);
        int cnt = ec_count9(e, n);
        acc += probs[f] * (float)cnt;
    }
    float t = ec_block_reduce(acc);
    if (threadIdx.x == 0) atomicAdd(out, t);
}

extern "C" void kernel_launch(void* const* d_in, const int* in_sizes, int n_in,
                              void* d_out, int out_size, void* d_ws, size_t ws_size,
                              hipStream_t stream) {
    const float* vertices = (const float*)d_in[0];
    const int*   faces    = (const int*)d_in[1];
    const float* probs    = (const float*)d_in[2];
    const int*   nbrs     = (const int*)d_in[3];
    int F = in_sizes[1] / 3;
    int K = (F > 0) ? (in_sizes[3] / F) : 0;
    int P = F * K;

    hipMemsetAsync(d_out, 0, sizeof(float), stream);

    size_t need = (size_t)F * 3 * sizeof(float4);
    int blocks = (P + 255) / 256;
    if (blocks > 2048) blocks = 2048;
    if (blocks < 1) blocks = 1;

    if (ws_size >= need) {
        float4* edges = (float4*)d_ws;
        ec_edges_kernel<<<(F + 255) / 256, 256, 0, stream>>>(vertices, faces, edges, F);
        ec_cross_ws_kernel<<<blocks, 256, 0, stream>>>(edges, probs, nbrs, (float*)d_out, F, K);
    } else {
        ec_cross_nows_kernel<<<blocks, 256, 0, stream>>>(vertices, faces, probs, nbrs,
                                                         (float*)d_out, F, K);
    }
}

// Round 2
// 44.059 us; speedup vs baseline: 1.1422x; 1.1422x over previous
//
#include <hip/hip_runtime.h>

// EdgeCrossingLoss: F faces, K neighbors each. Output = sum_f prob_f * crossings_f
// crossings counts (i,k,j) combos with t,u in [0,1]:
//   cp = e_i x ne_kj ; denom = cp.e_i ; t = (cp.ne_kj)/denom ; u = (cp.e_j)/denom.
// denom and t-numerator are analytically 0 => pure fp32 rounding residues.
// => numerics must match numpy op order exactly: no FMA (contract off), dot = ((x+y)+z).
// ec_count9 is BYTE-IDENTICAL to the R1 version that passed (absmax 8192 < 16138).

__device__ __forceinline__ int ec_count9(const float e[3][3], const float n[3][3]) {
#pragma clang fp contract(off)
    int cnt = 0;
#pragma unroll
    for (int i = 0; i < 3; ++i) {
#pragma unroll
        for (int j = 0; j < 3; ++j) {
            float c0 = e[i][1] * n[j][2] - e[i][2] * n[j][1];
            float c1 = e[i][2] * n[j][0] - e[i][0] * n[j][2];
            float c2 = e[i][0] * n[j][1] - e[i][1] * n[j][0];
            float d  = (c0 * e[i][0] + c1 * e[i][1]) + c2 * e[i][2];
            float tn = (c0 * n[j][0] + c1 * n[j][1]) + c2 * n[j][2];
            float un = (c0 * e[j][0] + c1 * e[j][1]) + c2 * e[j][2];
            bool pos = (tn >= 0.f) & (tn <= d) & (un >= 0.f) & (un <= d);
            bool neg = (tn <= 0.f) & (tn >= d) & (un <= 0.f) & (un >= d);
            bool hit = (d > 0.f) ? pos : ((d < 0.f) ? neg : false);
            cnt += hit ? 1 : 0;
        }
    }
    return cnt;
}

__global__ __launch_bounds__(256) void ec_edges_kernel(
    const float* __restrict__ vertices, const int* __restrict__ faces,
    float4* __restrict__ edges, float* __restrict__ out, int F) {
#pragma clang fp contract(off)
    int f = blockIdx.x * blockDim.x + threadIdx.x;
    if (f == 0) out[0] = 0.f;  // fold output zeroing into this dispatch
    if (f >= F) return;
    int i0 = faces[3 * f + 0], i1 = faces[3 * f + 1], i2 = faces[3 * f + 2];
    float ax = vertices[3 * i0 + 0], ay = vertices[3 * i0 + 1], az = vertices[3 * i0 + 2];
    float bx = vertices[3 * i1 + 0], by = vertices[3 * i1 + 1], bz = vertices[3 * i1 + 2];
    float cx = vertices[3 * i2 + 0], cy = vertices[3 * i2 + 1], cz = vertices[3 * i2 + 2];
    edges[3 * f + 0] = make_float4(bx - ax, by - ay, bz - az, 0.f);
    edges[3 * f + 1] = make_float4(cx - bx, cy - by, cz - bz, 0.f);
    edges[3 * f + 2] = make_float4(ax - cx, ay - cy, az - cz, 0.f);
}

__device__ __forceinline__ float ec_block_reduce(float acc) {
    for (int off = 32; off > 0; off >>= 1) acc += __shfl_down(acc, off);
    __shared__ float ws[4];
    int lane = threadIdx.x & 63, wv = threadIdx.x >> 6;
    if (lane == 0) ws[wv] = acc;
    __syncthreads();
    float t = 0.f;
    if (threadIdx.x == 0) t = (ws[0] + ws[1]) + (ws[2] + ws[3]);
    return t;
}

// 4 pairs per thread: one int4 neighbor load + 12 independent float4 gathers
// issued up-front (MLP), own-face edges amortized over 4 pairs.
__global__ __launch_bounds__(256) void ec_cross4_kernel(
    const float4* __restrict__ edges, const float* __restrict__ probs,
    const int4* __restrict__ nbrs4, float* __restrict__ out, int Q, int Kq) {
#pragma clang fp contract(off)
    int t = blockIdx.x * blockDim.x + threadIdx.x;
    float acc = 0.f;
    if (t < Q) {
        int4 nb4 = nbrs4[t];
        int f = t / Kq;
        float4 E0 = edges[3 * f + 0], E1 = edges[3 * f + 1], E2 = edges[3 * f + 2];
        int nbi[4] = {nb4.x, nb4.y, nb4.z, nb4.w};
        float4 N[4][3];
#pragma unroll
        for (int q = 0; q < 4; ++q) {
            int b = 3 * nbi[q];
            N[q][0] = edges[b + 0];
            N[q][1] = edges[b + 1];
            N[q][2] = edges[b + 2];
        }
        float e[3][3] = {{E0.x, E0.y, E0.z}, {E1.x, E1.y, E1.z}, {E2.x, E2.y, E2.z}};
        int cnt = 0;
#pragma unroll
        for (int q = 0; q < 4; ++q) {
            float n[3][3] = {{N[q][0].x, N[q][0].y, N[q][0].z},
                             {N[q][1].x, N[q][1].y, N[q][1].z},
                             {N[q][2].x, N[q][2].y, N[q][2].z}};
            cnt += ec_count9(e, n);
        }
        acc = probs[f] * (float)cnt;
    }
    float r = ec_block_reduce(acc);
    if (threadIdx.x == 0) atomicAdd(out, r);
}

// Fallback (K % 4 != 0): R1 grid-stride version, unchanged numerics.
__global__ __launch_bounds__(256) void ec_cross_ws_kernel(
    const float4* __restrict__ edges, const float* __restrict__ probs,
    const int* __restrict__ nbrs, float* __restrict__ out, int F, int K) {
#pragma clang fp contract(off)
    int P = F * K;
    int stride = gridDim.x * blockDim.x;
    float acc = 0.f;
    for (int p = blockIdx.x * blockDim.x + threadIdx.x; p < P; p += stride) {
        int f = p / K;
        int nb = nbrs[p];
        float4 E0 = edges[3 * f + 0], E1 = edges[3 * f + 1], E2 = edges[3 * f + 2];
        float4 N0 = edges[3 * nb + 0], N1 = edges[3 * nb + 1], N2 = edges[3 * nb + 2];
        float e[3][3] = {{E0.x, E0.y, E0.z}, {E1.x, E1.y, E1.z}, {E2.x, E2.y, E2.z}};
        float n[3][3] = {{N0.x, N0.y, N0.z}, {N1.x, N1.y, N1.z}, {N2.x, N2.y, N2.z}};
        int cnt = ec_count9(e, n);
        acc += probs[f] * (float)cnt;
    }
    float r = ec_block_reduce(acc);
    if (threadIdx.x == 0) atomicAdd(out, r);
}

__device__ __forceinline__ void ec_load_edges_direct(
    const float* __restrict__ v, const int* __restrict__ faces, int f, float e[3][3]) {
#pragma clang fp contract(off)
    int i0 = faces[3 * f + 0], i1 = faces[3 * f + 1], i2 = faces[3 * f + 2];
#pragma unroll
    for (int c = 0; c < 3; ++c) {
        float a = v[3 * i0 + c], b = v[3 * i1 + c], cc = v[3 * i2 + c];
        e[0][c] = b - a;
        e[1][c] = cc - b;
        e[2][c] = a - cc;
    }
}

// Fallback if ws too small for the edges buffer.
__global__ __launch_bounds__(256) void ec_cross_nows_kernel(
    const float* __restrict__ vertices, const int* __restrict__ faces,
    const float* __restrict__ probs, const int* __restrict__ nbrs,
    float* __restrict__ out, int F, int K) {
#pragma clang fp contract(off)
    int P = F * K;
    int stride = gridDim.x * blockDim.x;
    float acc = 0.f;
    for (int p = blockIdx.x * blockDim.x + threadIdx.x; p < P; p += stride) {
        int f = p / K;
        int nb = nbrs[p];
        float e[3][3], n[3][3];
        ec_load_edges_direct(vertices, faces, f, e);
        ec_load_edges_direct(vertices, faces, nb, n);
        int cnt = ec_count9(e, n);
        acc += probs[f] * (float)cnt;
    }
    float r = ec_block_reduce(acc);
    if (threadIdx.x == 0) atomicAdd(out, r);
}

extern "C" void kernel_launch(void* const* d_in, const int* in_sizes, int n_in,
                              void* d_out, int out_size, void* d_ws, size_t ws_size,
                              hipStream_t stream) {
    const float* vertices = (const float*)d_in[0];
    const int*   faces    = (const int*)d_in[1];
    const float* probs    = (const float*)d_in[2];
    const int*   nbrs     = (const int*)d_in[3];
    int F = in_sizes[1] / 3;
    int K = (F > 0) ? (in_sizes[3] / F) : 0;
    int P = F * K;

    size_t need = (size_t)F * 3 * sizeof(float4);

    if (ws_size >= need && K > 0 && (K % 4) == 0) {
        float4* edges = (float4*)d_ws;
        ec_edges_kernel<<<(F + 255) / 256, 256, 0, stream>>>(vertices, faces, edges,
                                                             (float*)d_out, F);
        int Q = P / 4;
        int blocks = (Q + 255) / 256;
        ec_cross4_kernel<<<blocks, 256, 0, stream>>>(edges, probs, (const int4*)nbrs,
                                                     (float*)d_out, Q, K / 4);
    } else if (ws_size >= need) {
        hipMemsetAsync(d_out, 0, sizeof(float), stream);
        float4* edges = (float4*)d_ws;
        ec_edges_kernel<<<(F + 255) / 256, 256, 0, stream>>>(vertices, faces, edges,
                                                             (float*)d_out, F);
        int blocks = (P + 255) / 256; if (blocks > 2048) blocks = 2048; if (blocks < 1) blocks = 1;
        ec_cross_ws_kernel<<<blocks, 256, 0, stream>>>(edges, probs, nbrs, (float*)d_out, F, K);
    } else {
        hipMemsetAsync(d_out, 0, sizeof(float), stream);
        int blocks = (P + 255) / 256; if (blocks > 2048) blocks = 2048; if (blocks < 1) blocks = 1;
        ec_cross_nows_kernel<<<blocks, 256, 0, stream>>>(vertices, faces, probs, nbrs,
                                                         (float*)d_out, F, K);
    }
}